// Round 17
// baseline (102.648 us; speedup 1.0000x reference)
//
#include <hip/hip_runtime.h>

// FFF tree traversal, round 17: r16 numerics/structure frozen; scheduling
// and address-path changes only.
//  (1) 128-thread blocks (2 waves/block, 16384 blocks): finer dispatch
//      quantum -> more independent workgroups/CU, no 4-wave block tail,
//      better desync of the 11-level serial chains.
//  (2) w1/w2 interleaved per node (2KB stride: [w1 1KB][w2 1KB]) + scales
//      packed float2 -> one base addr + one s_load_dwordx2 per level.
// Traffic invariant: 720 MB weight gathers (r11/r15: any extra loses).
// Frozen: i8 x + sdot4, DPP reduces, next-level load before y-accum,
// biased-u8 w2 + corr, EPS=0.035 fp32 fallback (x reloaded), nt x loads,
// nt y stores (r16: FETCH -23 MB, WRITE exact).

typedef float        f32x4 __attribute__((ext_vector_type(4)));
typedef unsigned int u32x4 __attribute__((ext_vector_type(4)));

#define FFF_BATCH  32768
#define FFF_NIN    1024
#define FFF_NOUT   1024
#define FFF_LEVELS 11
#define FFF_NODES  2047
#define FFF_EPS    0.035f

__device__ __forceinline__ f32x4 ld_nt4f(const f32x4* p) { return __builtin_nontemporal_load(p); }
__device__ __forceinline__ float ub(unsigned d, int k) {
    return (float)((d >> (8 * k)) & 0xffu);   // -> v_cvt_f32_ubyte[k]
}

__device__ __forceinline__ int sdot4(unsigned a, unsigned b, int c) {
#if __has_builtin(__builtin_amdgcn_sdot4)
    return __builtin_amdgcn_sdot4((int)a, (int)b, c, false);
#else
#pragma unroll
    for (int k = 0; k < 4; ++k) {
        const int ai = (int)(a << (24 - 8 * k)) >> 24;
        const int bi = (int)(b << (24 - 8 * k)) >> 24;
        c += ai * bi;
    }
    return c;
#endif
}

template<int CTRL>
__device__ __forceinline__ float dpp_add(float v) {
    const int t = __builtin_amdgcn_update_dpp(0, __float_as_int(v), CTRL, 0xF, 0xF, true);
    return v + __int_as_float(t);
}
__device__ __forceinline__ float wave_sum(float v) {
    v = dpp_add<0x111>(v); v = dpp_add<0x112>(v);
    v = dpp_add<0x114>(v); v = dpp_add<0x118>(v);
    v = dpp_add<0x142>(v); v = dpp_add<0x143>(v);
    return __int_as_float(__builtin_amdgcn_readlane(__float_as_int(v), 63));
}
template<int CTRL>
__device__ __forceinline__ int dpp_addi(int v) {
    return v + __builtin_amdgcn_update_dpp(0, v, CTRL, 0xF, 0xF, true);
}
__device__ __forceinline__ int wave_sum_i(int v) {
    v = dpp_addi<0x111>(v); v = dpp_addi<0x112>(v);
    v = dpp_addi<0x114>(v); v = dpp_addi<0x118>(v);
    v = dpp_addi<0x142>(v); v = dpp_addi<0x143>(v);
    return __builtin_amdgcn_readlane(v, 63);
}
template<int CTRL>
__device__ __forceinline__ float dpp_max(float v) {
    const int t = __builtin_amdgcn_update_dpp(0, __float_as_int(v), CTRL, 0xF, 0xF, true);
    return fmaxf(v, __int_as_float(t));
}
__device__ __forceinline__ float wave_max(float v) {   // v >= 0
    v = dpp_max<0x111>(v); v = dpp_max<0x112>(v);
    v = dpp_max<0x114>(v); v = dpp_max<0x118>(v);
    v = dpp_max<0x142>(v); v = dpp_max<0x143>(v);
    return __int_as_float(__builtin_amdgcn_readlane(__float_as_int(v), 63));
}

// ---- prep: interleaved per-node [w1-i8 1KB][w2-u8 1KB] + float2 scales ----
// dword t of each 1KB half <- src f32x4 index si = 64*(t&3)+(t>>2), so in
// main, lane's dwords 4*lane..+3 pair with xq[c][k] <- x[256c+4*lane+k].
__global__ void fff_quant_u8(const float* __restrict__ w1, const float* __restrict__ w2,
                             unsigned char* __restrict__ q, float2* __restrict__ sc)
{
    const int node = blockIdx.x;
    const int t    = threadIdx.x;          // 256
    const int wave = t >> 6;
    const int lane = t & 63;

    const f32x4* r1 = reinterpret_cast<const f32x4*>(w1 + (size_t)node * FFF_NIN);
    const f32x4* r2 = reinterpret_cast<const f32x4*>(w2 + (size_t)node * FFF_NOUT);
    const int si = 64 * (t & 3) + (t >> 2);
    const f32x4 v1 = r1[si];
    const f32x4 v2 = r2[si];

    float m1 = 0.f, m2 = 0.f;
#pragma unroll
    for (int k = 0; k < 4; ++k) {
        m1 = fmaxf(m1, fabsf(v1[k]));
        m2 = fmaxf(m2, fabsf(v2[k]));
    }
#pragma unroll
    for (int m = 1; m < 64; m <<= 1) {
        m1 = fmaxf(m1, __shfl_xor(m1, m, 64));
        m2 = fmaxf(m2, __shfl_xor(m2, m, 64));
    }
    __shared__ float sm1[4], sm2[4];
    if (lane == 0) { sm1[wave] = m1; sm2[wave] = m2; }
    __syncthreads();
    m1 = fmaxf(fmaxf(sm1[0], sm1[1]), fmaxf(sm1[2], sm1[3]));
    m2 = fmaxf(fmaxf(sm2[0], sm2[1]), fmaxf(sm2[2], sm2[3]));

    const float st1 = (m1 > 0.f) ? m1 / 127.f : 1.f;
    const float st2 = (m2 > 0.f) ? m2 / 127.f : 1.f;
    if (t == 0) sc[node] = make_float2(st1, st2);

    unsigned d1 = 0, d2 = 0;
#pragma unroll
    for (int k = 0; k < 4; ++k) {
        const int i1 = (int)rintf(v1[k] / st1);         // signed, [-127,127]
        const int u2 = (int)rintf(v2[k] / st2) + 128;   // biased, [1,255]
        d1 |= ((unsigned)i1 & 0xffu) << (8 * k);
        d2 |= ((unsigned)u2 & 0xffu) << (8 * k);
    }
    unsigned* qw = reinterpret_cast<unsigned*>(q + (size_t)node * 2048);
    qw[t]       = d1;   // w1 half
    qw[256 + t] = d2;   // w2 half
}

// ---- main fused kernel: 1 row/wave, 2 waves/block, rolled level loop ----
__global__ __launch_bounds__(128, 8) void fff_main_u8(
    const float*         __restrict__ x,
    const unsigned char* __restrict__ q,
    const float2*        __restrict__ sc,
    const float*         __restrict__ w1f,   // fp32 w1 for the EPS fallback
    float*               __restrict__ y)
{
    const int row  = blockIdx.x * 2 + (threadIdx.x >> 6);
    const int lane = threadIdx.x & 63;

    // coalesced x: xv[c] = elements 256c + 4*lane ..+3
    const f32x4* x4 = reinterpret_cast<const f32x4*>(x + (size_t)row * FFF_NIN);

    // per-row i8 quantization of x (fp32 x not kept live; fallback reloads)
    unsigned xq[4];
    float stx;
    {
        f32x4 xv[4];
#pragma unroll
        for (int c = 0; c < 4; ++c) xv[c] = ld_nt4f(&x4[c * 64 + lane]);
        float mx = 0.f;
#pragma unroll
        for (int c = 0; c < 4; ++c)
#pragma unroll
            for (int k = 0; k < 4; ++k) mx = fmaxf(mx, fabsf(xv[c][k]));
        mx = wave_max(mx);
        stx = (mx > 0.f) ? mx / 127.f : 1.f;
        const float inv = (mx > 0.f) ? 127.f / mx : 0.f;
#pragma unroll
        for (int c = 0; c < 4; ++c) {
            unsigned pk = 0;
#pragma unroll
            for (int k = 0; k < 4; ++k)
                pk |= ((unsigned)(int)rintf(xv[c][k] * inv) & 0xffu) << (8 * k);
            xq[c] = pk;
        }
    }

    f32x4 acc[4];
#pragma unroll
    for (int c = 0; c < 4; ++c) acc[c] = (f32x4)(0.f);
    float corr = 0.f;

    int node = 0;
    const unsigned char* nb = q;                 // node 0 base
    u32x4 d1 = *reinterpret_cast<const u32x4*>(nb + lane * 16);
    u32x4 d2 = *reinterpret_cast<const u32x4*>(nb + 1024 + lane * 16);
    float2 s12 = sc[0];

#pragma unroll 1
    for (int l = 0; l < FFF_LEVELS; ++l) {
        // ---- i8 dot: 4 sdot4 per lane, exact i32 ----
        int idot = 0;
#pragma unroll
        for (int c = 0; c < 4; ++c) idot = sdot4(xq[c], d1[c], idot);

        // ---- DPP integer reduce; score uniform ----
        float p = (float)wave_sum_i(idot) * (stx * s12.x);

        // ---- rare wave-uniform fp32 recompute for near-zero scores ----
        if (__builtin_expect(fabsf(p) < FFF_EPS, 0)) {
            const f32x4* w14 = reinterpret_cast<const f32x4*>(w1f + (size_t)node * FFF_NIN);
            float s = 0.f;
#pragma unroll
            for (int c = 0; c < 4; ++c) {
                const f32x4 xc = ld_nt4f(&x4[c * 64 + lane]);
                const f32x4 w  = w14[c * 64 + lane];
                s = fmaf(xc[0], w[0], s);
                s = fmaf(xc[1], w[1], s);
                s = fmaf(xc[2], w[2], s);
                s = fmaf(xc[3], w[3], s);
            }
            p = wave_sum(s);
        }

        // ---- advance + issue next level's loads before the y-accum ----
        const int next = 2 * node + 1 + ((p > 0.f) ? 1 : 0);
        u32x4 nd1 = d1, nd2 = d2;
        float2 ns12 = s12;
        if (l < FFF_LEVELS - 1) {
            const int un = __builtin_amdgcn_readfirstlane(next);
            const unsigned char* b2 = q + (size_t)un * 2048;
            nd1  = *reinterpret_cast<const u32x4*>(b2 + lane * 16);
            nd2  = *reinterpret_cast<const u32x4*>(b2 + 1024 + lane * 16);
            ns12 = sc[un];
        }

        // ---- y accumulate (hides the child-load latency) ----
        const float s2l = p * s12.y;
        corr = fmaf(s2l, 128.f, corr);
#pragma unroll
        for (int c = 0; c < 4; ++c) {
#pragma unroll
            for (int k = 0; k < 4; ++k)
                acc[c][k] = fmaf(s2l, ub(d2[c], k), acc[c][k]);
        }

        node = next;
        d1 = nd1; d2 = nd2; s12 = ns12;
    }

    // coalesced nontemporal y stores (full 128B lines; keep L2 for weights)
    f32x4* y4 = reinterpret_cast<f32x4*>(y + (size_t)row * FFF_NOUT);
#pragma unroll
    for (int c = 0; c < 4; ++c) {
        f32x4 o;
        o[0] = acc[c][0] - corr; o[1] = acc[c][1] - corr;
        o[2] = acc[c][2] - corr; o[3] = acc[c][3] - corr;
        __builtin_nontemporal_store(o, &y4[c * 64 + lane]);
    }
}

// ---- safety fallback: proven round-1 fp32 fused kernel ----
__global__ __launch_bounds__(256, 4) void fff_fused_f32(
    const float* __restrict__ x, const float* __restrict__ w1s,
    const float* __restrict__ w2s, float* __restrict__ y)
{
    const int row  = blockIdx.x * 4 + (threadIdx.x >> 6);
    const int lane = threadIdx.x & 63;
    const f32x4* x4 = reinterpret_cast<const f32x4*>(x + (size_t)row * FFF_NIN);
    f32x4 xv[4];
#pragma unroll
    for (int c = 0; c < 4; ++c) xv[c] = x4[c * 64 + lane];
    f32x4 acc[4];
#pragma unroll
    for (int c = 0; c < 4; ++c) acc[c] = (f32x4)(0.f);
    int node = 0;
#pragma unroll 1
    for (int l = 0; l < FFF_LEVELS; ++l) {
        const f32x4* w14 = reinterpret_cast<const f32x4*>(w1s + (size_t)node * FFF_NIN);
        const f32x4* w24 = reinterpret_cast<const f32x4*>(w2s + (size_t)node * FFF_NOUT);
        f32x4 wv[4], uv[4];
#pragma unroll
        for (int c = 0; c < 4; ++c) { wv[c] = w14[c * 64 + lane]; uv[c] = w24[c * 64 + lane]; }
        float p = 0.f;
#pragma unroll
        for (int c = 0; c < 4; ++c) {
            p = fmaf(xv[c][0], wv[c][0], p); p = fmaf(xv[c][1], wv[c][1], p);
            p = fmaf(xv[c][2], wv[c][2], p); p = fmaf(xv[c][3], wv[c][3], p);
        }
#pragma unroll
        for (int m = 1; m < 64; m <<= 1) p += __shfl_xor(p, m, 64);
#pragma unroll
        for (int c = 0; c < 4; ++c) {
            acc[c][0] = fmaf(p, uv[c][0], acc[c][0]); acc[c][1] = fmaf(p, uv[c][1], acc[c][1]);
            acc[c][2] = fmaf(p, uv[c][2], acc[c][2]); acc[c][3] = fmaf(p, uv[c][3], acc[c][3]);
        }
        node = node * 2 + 1 + ((p > 0.f) ? 1 : 0);
    }
    f32x4* y4 = reinterpret_cast<f32x4*>(y + (size_t)row * FFF_NOUT);
#pragma unroll
    for (int c = 0; c < 4; ++c) y4[c * 64 + lane] = acc[c];
}

extern "C" void kernel_launch(void* const* d_in, const int* in_sizes, int n_in,
                              void* d_out, int out_size, void* d_ws, size_t ws_size,
                              hipStream_t stream) {
    const float* x   = (const float*)d_in[0];
    const float* w1s = (const float*)d_in[1];
    const float* w2s = (const float*)d_in[2];
    float* y = (float*)d_out;

    // ws layout (16B-aligned blocks): sc (float2[2047], padded) | q (2KB/node)
    const size_t sc_bytes = 16384;
    const size_t q_bytes  = (size_t)FFF_NODES * 2048;          // 4,192,256
    const size_t need = sc_bytes + q_bytes;                    // ~4.21 MB

    if (ws_size >= need) {
        float2* scp = (float2*)d_ws;
        unsigned char* q = (unsigned char*)d_ws + sc_bytes;
        fff_quant_u8<<<FFF_NODES, 256, 0, stream>>>(w1s, w2s, q, scp);
        fff_main_u8<<<FFF_BATCH / 2, 128, 0, stream>>>(x, q, scp, w1s, y);
    } else {
        fff_fused_f32<<<FFF_BATCH / 4, 256, 0, stream>>>(x, w1s, w2s, y);
    }
}